// Round 2
// baseline (151.010 us; speedup 1.0000x reference)
//
#include <hip/hip_runtime.h>

// Chamfer loss: pred (2048,8,3) vs gt (2048,8,3) fp32. N=16384 pts/side.
// out = mean(min_m d) + mean(min_n d); 8-corner group-mean == global mean.
//
// R5 (MFMA): d2 = |x|^2+|y|^2-2x.y is a K=3 GEMM. VALU brute force has a
// hard floor of 3 FMA/pair * 536.9M pairs ~ 23.9us; MFMA breaks it.
//  - 3-way bf16 split (x=xh+xm+xl) packed along MFMA K: 6 significant
//    cross-combos x 3 dims = 18 slots, -|x|^2/2 vs B=1 (3), -|y|^2/2 vs
//    A=1 (3) -> one mfma_f32_16x16x32_bf16 yields acc = -d2/2 (~1e-6 err).
//  - one S=pred.gt^T matrix serves BOTH directions (row-min + col-min);
//    output = mean of mins => invariant to any consistent layout transpose.
//  - B-frags (wave's 256 y) held in 64 VGPRs; A-frag 1 global load/x-tile;
//    no LDS in hot loop. Merge cost: y-tiles paired, max3 merges = 4 VALU
//    ops/MFMA; shfl_xor flushes ride the LDS pipe (ds_bpermute).
//  - pack_points precomputes packed fragment rows in ws (+2.25MB).
//  - keeps R4's verified memset(0x7F) init + last-block ticket reduce.

#define NPTS   16384
#define BLOCK  256
#define XCH    256            // x-points per block (16 tiles)
#define YCH    1024           // y-points per block (4 waves x 256)
#define YW     256            // y-points per wave (16 tiles)
#define NXC    (NPTS / XCH)   // 64
#define NYC    (NPTS / YCH)   // 16
#define GRID   (NXC * NYC)    // 1024 blocks
#define TICKET0 0x7F7F7F7Fu   // memset(0x7F) pattern = ticket initial value
#define PACK_OFF (1 << 18)    // Apack at ws+256KB; Bpack follows (1MB each)

typedef __attribute__((ext_vector_type(8))) short bf16x8;
typedef __attribute__((ext_vector_type(4))) float f32x4;

__device__ inline unsigned short f2bf(float f) {  // fp32 -> bf16 RNE
    unsigned int u = __float_as_uint(f);
    return (unsigned short)((u + 0x7FFFu + ((u >> 16) & 1u)) >> 16);
}
__device__ inline float bf2f(unsigned short h) {
    return __uint_as_float((unsigned int)h << 16);
}
__device__ inline void split3(float v, unsigned short* s) {
    unsigned short h = f2bf(v);  float r = v - bf2f(h);
    unsigned short m = f2bf(r);  r -= bf2f(m);
    s[0] = h; s[1] = m; s[2] = f2bf(r);
}

// K-slot map (shared by A and B rows; identical order is what makes any
// consistent lane->K bijection cancel):
//   s = c*3+d, c<6: cross combos (i,j) = (h,h)(h,m)(m,h)(h,l)(m,m)(l,h)
//   s = 18..20: A = split3(-|x|^2/2), B = 1
//   s = 21..23: A = 1, B = split3(-|y|^2/2)
//   s = 24..31: 0        => acc = x.y - |x|^2/2 - |y|^2/2 = -d2/2
__global__ __launch_bounds__(256) void pack_points(
        const float* __restrict__ pred, const float* __restrict__ gt,
        unsigned short* __restrict__ Apack, unsigned short* __restrict__ Bpack) {
    const int i = blockIdx.x * 256 + threadIdx.x;
    if (i >= NPTS) return;
    const int CI[6] = {0, 0, 1, 0, 1, 2};
    const int CJ[6] = {0, 1, 0, 2, 1, 0};
    const unsigned short ONE = 0x3F80;  // bf16 1.0

    float p[3] = {pred[3*i], pred[3*i+1], pred[3*i+2]};
    float q[3] = {gt[3*i],   gt[3*i+1],   gt[3*i+2]};
    unsigned short xs[3][3], ys[3][3], nx[3], ny[3];
#pragma unroll
    for (int d = 0; d < 3; ++d) {
        unsigned short t[3];
        split3(p[d], t); xs[0][d] = t[0]; xs[1][d] = t[1]; xs[2][d] = t[2];
        split3(q[d], t); ys[0][d] = t[0]; ys[1][d] = t[1]; ys[2][d] = t[2];
    }
    split3(-0.5f * (p[0]*p[0] + p[1]*p[1] + p[2]*p[2]), nx);
    split3(-0.5f * (q[0]*q[0] + q[1]*q[1] + q[2]*q[2]), ny);

    unsigned short a[32], b[32];
#pragma unroll
    for (int c = 0; c < 6; ++c)
#pragma unroll
        for (int d = 0; d < 3; ++d) {
            a[c*3+d] = xs[CI[c]][d];
            b[c*3+d] = ys[CJ[c]][d];
        }
#pragma unroll
    for (int k = 0; k < 3; ++k) {
        a[18+k] = nx[k]; b[18+k] = ONE;
        a[21+k] = ONE;   b[21+k] = ny[k];
    }
#pragma unroll
    for (int k = 24; k < 32; ++k) { a[k] = 0; b[k] = 0; }

    // pack to dwords (static indices -> stays in regs), 4x16B stores each
    unsigned int aw[16], bw[16];
#pragma unroll
    for (int k = 0; k < 16; ++k) {
        aw[k] = (unsigned int)a[2*k] | ((unsigned int)a[2*k+1] << 16);
        bw[k] = (unsigned int)b[2*k] | ((unsigned int)b[2*k+1] << 16);
    }
    uint4* pa = reinterpret_cast<uint4*>(Apack + (size_t)i * 32);
    uint4* pb = reinterpret_cast<uint4*>(Bpack + (size_t)i * 32);
#pragma unroll
    for (int k = 0; k < 4; ++k) {
        pa[k] = make_uint4(aw[4*k], aw[4*k+1], aw[4*k+2], aw[4*k+3]);
        pb[k] = make_uint4(bw[4*k], bw[4*k+1], bw[4*k+2], bw[4*k+3]);
    }
}

__global__ __launch_bounds__(BLOCK, 3) void chamfer_mfma(
        const unsigned short* __restrict__ Apack,
        const unsigned short* __restrict__ Bpack,
        unsigned int* __restrict__ mins, float* __restrict__ out) {
    const int lane = threadIdx.x & 63;
    const int wave = threadIdx.x >> 6;
    const int col  = lane & 15;
    const int kg   = lane >> 4;
    const int xbase = blockIdx.x * XCH;
    const int ybase = blockIdx.y * YCH + wave * YW;
    unsigned int* __restrict__ minsP  = mins;
    unsigned int* __restrict__ minsG  = mins + NPTS;
    unsigned int* __restrict__ ticket = mins + 2 * NPTS;

    __shared__ float wsum[BLOCK / 64];
    __shared__ int   lastflag;

    const f32x4 z4 = {0.0f, 0.0f, 0.0f, 0.0f};

    // wave-resident B fragments: 16 y-tiles x 4 VGPR = 64 VGPRs
    bf16x8 bfr[16];
#pragma unroll
    for (int yt = 0; yt < 16; ++yt)
        bfr[yt] = *reinterpret_cast<const bf16x8*>(
            Bpack + (size_t)(ybase + yt * 16 + col) * 32 + kg * 8);
    float cmax[16];
#pragma unroll
    for (int yt = 0; yt < 16; ++yt) cmax[yt] = -3.0e38f;

#pragma unroll 1
    for (int xt = 0; xt < 16; ++xt) {
        bf16x8 af = *reinterpret_cast<const bf16x8*>(
            Apack + (size_t)(xbase + xt * 16 + col) * 32 + kg * 8);
        float rmax[4] = {-3.0e38f, -3.0e38f, -3.0e38f, -3.0e38f};
#pragma unroll
        for (int yt = 0; yt < 16; yt += 2) {
            f32x4 A = __builtin_amdgcn_mfma_f32_16x16x32_bf16(af, bfr[yt],     z4, 0, 0, 0);
            f32x4 B = __builtin_amdgcn_mfma_f32_16x16x32_bf16(af, bfr[yt + 1], z4, 0, 0, 0);
            rmax[0] = fmaxf(fmaxf(A.x, B.x), rmax[0]);  // v_max3_f32
            rmax[1] = fmaxf(fmaxf(A.y, B.y), rmax[1]);
            rmax[2] = fmaxf(fmaxf(A.z, B.z), rmax[2]);
            rmax[3] = fmaxf(fmaxf(A.w, B.w), rmax[3]);
            cmax[yt]     = fmaxf(fmaxf(A.x, A.y), cmax[yt]);
            cmax[yt]     = fmaxf(fmaxf(A.z, A.w), cmax[yt]);
            cmax[yt + 1] = fmaxf(fmaxf(B.x, B.y), cmax[yt + 1]);
            cmax[yt + 1] = fmaxf(fmaxf(B.z, B.w), cmax[yt + 1]);
        }
        // row flush: butterfly over the 16 cols (shfl = ds_bpermute, LDS pipe)
#pragma unroll
        for (int i = 0; i < 4; ++i) {
            float v = rmax[i];
            v = fmaxf(v, __shfl_xor(v, 1, 64));
            v = fmaxf(v, __shfl_xor(v, 2, 64));
            v = fmaxf(v, __shfl_xor(v, 4, 64));
            v = fmaxf(v, __shfl_xor(v, 8, 64));
            rmax[i] = v;
        }
        if (col == 0) {
#pragma unroll
            for (int i = 0; i < 4; ++i) {
                float d2 = fmaxf(-2.0f * rmax[i], 0.0f);  // acc = -d2/2
                atomicMin(&minsP[xbase + xt * 16 + kg * 4 + i], __float_as_uint(d2));
            }
        }
    }
    // col flush: reduce across the 4 row-groups (lane bits 4,5)
#pragma unroll
    for (int yt = 0; yt < 16; ++yt) {
        float v = cmax[yt];
        v = fmaxf(v, __shfl_xor(v, 16, 64));
        v = fmaxf(v, __shfl_xor(v, 32, 64));
        if (kg == 0) {
            float d2 = fmaxf(-2.0f * v, 0.0f);
            atomicMin(&minsG[ybase + yt * 16 + col], __float_as_uint(d2));
        }
    }

    // --- last-block reduction (verified in R4) ----------------------------
    __syncthreads();  // drains vmcnt: this block's atomics are done
    const int tid = threadIdx.x;
    if (tid == 0) {
        __threadfence();
        unsigned int old = atomicSub(ticket, 1u);
        lastflag = (old == TICKET0 - (GRID - 1));
    }
    __syncthreads();
    if (!lastflag) return;

    __threadfence();  // acquire side of the ticket chain
    float s = 0.0f;
#pragma unroll 4
    for (int i = tid; i < 2 * NPTS; i += BLOCK) {
        unsigned int m = __hip_atomic_load(&mins[i], __ATOMIC_RELAXED,
                                           __HIP_MEMORY_SCOPE_AGENT);
        s += sqrtf(__uint_as_float(m));
    }
#pragma unroll
    for (int off = 32; off > 0; off >>= 1)
        s += __shfl_down(s, off, 64);
    if ((tid & 63) == 0) wsum[tid >> 6] = s;
    __syncthreads();
    if (tid == 0)
        out[0] = (wsum[0] + wsum[1] + wsum[2] + wsum[3]) * (1.0f / (float)NPTS);
}

extern "C" void kernel_launch(void* const* d_in, const int* in_sizes, int n_in,
                              void* d_out, int out_size, void* d_ws, size_t ws_size,
                              hipStream_t stream) {
    const float* pred = (const float*)d_in[0];
    const float* gt   = (const float*)d_in[1];
    float* out        = (float*)d_out;
    unsigned int* mins = (unsigned int*)d_ws;  // 2*NPTS mins + 1 ticket
    // packed fragment rows: 16384 x 32 bf16 = 1MB each; total ws use 2.25MB
    unsigned short* Apack = (unsigned short*)((char*)d_ws + PACK_OFF);
    unsigned short* Bpack = Apack + (size_t)NPTS * 32;

    // 0x7F7F7F7F = 3.39e38f (> any d2) for the min slots AND the ticket start
    hipMemsetAsync(d_ws, 0x7F, (2 * NPTS + 1) * sizeof(unsigned int), stream);
    hipLaunchKernelGGL(pack_points, dim3(NPTS / 256), dim3(256), 0, stream,
                       pred, gt, Apack, Bpack);
    hipLaunchKernelGGL(chamfer_mfma, dim3(NXC, NYC), dim3(BLOCK), 0, stream,
                       Apack, Bpack, mins, out);
}

// Round 3
// 97.017 us; speedup vs baseline: 1.5565x; 1.5565x over previous
//
#include <hip/hip_runtime.h>

// Chamfer loss: pred (2048,8,3) vs gt (2048,8,3) fp32. N=16384 pts/side.
// out = mean(min_m d) + mean(min_n d); 8-corner group-mean == global mean.
//
// R6: two-pass row-min MFMA, zero atomics in the hot path.
//  - keeps R5's VERIFIED bf16 3-way-split K-packing (absmax 0.0):
//    acc = x.y - |x|^2/2 - |y|^2/2 = -d2/2 in one mfma_f32_16x16x32_bf16.
//  - R5 post-mortem: 95us @ 15% VALUBusy came from (a) 2.1M device-scope
//    atomicMin (52MB fabric writes), (b) 1.2M ds_bpermute chains in the hot
//    loop, (c) a single-block 32K-uncached-load tail reduce. All removed:
//    * two passes (dir = blockIdx.z) -> row-min only, partial-min arrays
//      written with plain coalesced stores (no atomics at all).
//    * col-reduce once per wave via DPP row_ror max (VALU pipe, not LDS).
//    * parallel 128-block reduce kernel (launches are ~free: fixed ~50us
//      harness overhead dominates total regardless of launch count).
//  - B-frags staged global->reg->LDS double-buffered (T14 split); one
//    ds_read_b128 feeds 8 MFMAs (8 x-tiles/wave in VGPR) so LDS pipe
//    (~12K cyc/CU) balances MFMA (~10K cyc/CU). Merge = 2 v_max3/MFMA.

#define NPTS   16384
#define BLOCKB 512
#define WAVES  8
#define XT_W   8                  // x-tiles per wave (A-frags in 32 VGPR)
#define XPB    (WAVES * XT_W * 16)  // 1024 x-points per block
#define NXB    (NPTS / XPB)       // 16
#define NYCH   16                 // y-chunks (partial-min sets)
#define YCH    (NPTS / NYCH)      // 1024 y-points per chunk
#define SUBT   8                  // y-tiles per LDS buffer (8 KB)
#define SUBPTS (SUBT * 16)        // 128
#define NSUB   (YCH / SUBPTS)     // 8
#define ONEBF  0x3F80             // bf16 1.0

// ws layout: [0,1MB) Ppa | [1,2MB) Pgb | [2,3MB) Pga | [3,4MB) Ppb
//            [4,6MB) partials float[2][NYCH][NPTS]
#define WS_PGB (1u << 20)
#define WS_PGA (2u << 20)
#define WS_PPB (3u << 20)
#define WS_PART (4u << 20)

typedef __attribute__((ext_vector_type(8))) short bf16x8;
typedef __attribute__((ext_vector_type(4))) float f32x4;

__device__ inline unsigned short f2bf(float f) {  // fp32 -> bf16 RNE
    unsigned int u = __float_as_uint(f);
    return (unsigned short)((u + 0x7FFFu + ((u >> 16) & 1u)) >> 16);
}
__device__ inline float bf2f(unsigned short h) {
    return __uint_as_float((unsigned int)h << 16);
}
__device__ inline void split3(float v, unsigned short* s) {
    unsigned short h = f2bf(v);  float r = v - bf2f(h);
    unsigned short m = f2bf(r);  r -= bf2f(m);
    s[0] = h; s[1] = m; s[2] = f2bf(r);
}

// K-slot map (identical order on A and B rows => lane->K bijection cancels):
//   s=c*3+d, c<6: cross combos (i,j)=(h,h)(h,m)(m,h)(h,l)(m,m)(l,h)
//   s=18..20: a=split3(-|p|^2/2), b=1 ; s=21..23: a=1, b=split3(-|p|^2/2)
//   s=24..31: 0   => S[r][c] = x.y - |x|^2/2 - |y|^2/2 = -d2/2
__device__ inline void build_rows(const float p[3], unsigned short* a,
                                  unsigned short* b) {
    const int CI[6] = {0, 0, 1, 0, 1, 2};
    const int CJ[6] = {0, 1, 0, 2, 1, 0};
    unsigned short xs[3][3], nn[3], t[3];
#pragma unroll
    for (int d = 0; d < 3; ++d) {
        split3(p[d], t);
        xs[0][d] = t[0]; xs[1][d] = t[1]; xs[2][d] = t[2];
    }
    split3(-0.5f * (p[0]*p[0] + p[1]*p[1] + p[2]*p[2]), nn);
#pragma unroll
    for (int c = 0; c < 6; ++c)
#pragma unroll
        for (int d = 0; d < 3; ++d) {
            a[c*3+d] = xs[CI[c]][d];
            b[c*3+d] = xs[CJ[c]][d];
        }
#pragma unroll
    for (int k = 0; k < 3; ++k) {
        a[18+k] = nn[k];  b[18+k] = ONEBF;
        a[21+k] = ONEBF;  b[21+k] = nn[k];
    }
#pragma unroll
    for (int k = 24; k < 32; ++k) { a[k] = 0; b[k] = 0; }
}

__device__ inline void store_row(unsigned short* dst, const unsigned short* s) {
    unsigned int w[16];
#pragma unroll
    for (int k = 0; k < 16; ++k)
        w[k] = (unsigned int)s[2*k] | ((unsigned int)s[2*k+1] << 16);
    uint4* d4 = reinterpret_cast<uint4*>(dst);
#pragma unroll
    for (int k = 0; k < 4; ++k)
        d4[k] = make_uint4(w[4*k], w[4*k+1], w[4*k+2], w[4*k+3]);
}

__global__ __launch_bounds__(256) void pack_points(
        const float* __restrict__ pred, const float* __restrict__ gt,
        unsigned short* __restrict__ Ppa, unsigned short* __restrict__ Pgb,
        unsigned short* __restrict__ Pga, unsigned short* __restrict__ Ppb) {
    const int i = blockIdx.x * 256 + threadIdx.x;
    if (i >= NPTS) return;
    float p[3] = {pred[3*i], pred[3*i+1], pred[3*i+2]};
    float q[3] = {gt[3*i],   gt[3*i+1],   gt[3*i+2]};
    unsigned short ra[32], rb[32];
    build_rows(p, ra, rb);
    store_row(Ppa + (size_t)i * 32, ra);
    store_row(Ppb + (size_t)i * 32, rb);
    build_rows(q, ra, rb);
    store_row(Pga + (size_t)i * 32, ra);
    store_row(Pgb + (size_t)i * 32, rb);
}

// DPP rotate-max within 16-lane rows: after ror 1,2,4,8 every lane holds the
// row max. VALU-only (v_mov_b32_dpp + v_max) -- keeps the LDS pipe free.
template <int CTRL>
__device__ inline float rormax(float v) {
    int t = __builtin_amdgcn_update_dpp(0, __float_as_int(v), CTRL, 0xF, 0xF,
                                        false);
    return fmaxf(v, __int_as_float(t));
}

__global__ __launch_bounds__(BLOCKB, 4) void chamfer_part(
        const unsigned short* __restrict__ Ppa,
        const unsigned short* __restrict__ Pgb,
        const unsigned short* __restrict__ Pga,
        const unsigned short* __restrict__ Ppb,
        float* __restrict__ part) {
    const int xb  = blockIdx.x;
    const int yc  = blockIdx.y;
    const int dir = blockIdx.z;
    const unsigned short* __restrict__ Ap = dir ? Pga : Ppa;  // X = rows
    const unsigned short* __restrict__ Bp = dir ? Ppb : Pgb;  // Y = cols
    const int tid = threadIdx.x;
    const int lane = tid & 63, w = tid >> 6;
    const int col = lane & 15, kg = lane >> 4;

    __shared__ __align__(16) char lbuf[2][SUBT * 16 * 64];  // 2 x 8 KB

    // A-frags: this wave's 8 x-tiles, resident in 32 VGPRs
    const int xt0 = xb * (WAVES * XT_W) + w * XT_W;
    bf16x8 af[XT_W];
#pragma unroll
    for (int xi = 0; xi < XT_W; ++xi)
        af[xi] = *reinterpret_cast<const bf16x8*>(
            Ap + (size_t)((xt0 + xi) * 16 + col) * 32 + kg * 8);

    f32x4 rmax[XT_W];
#pragma unroll
    for (int xi = 0; xi < XT_W; ++xi)
        rmax[xi] = (f32x4){-3.0e38f, -3.0e38f, -3.0e38f, -3.0e38f};

    const f32x4 z4 = {0.0f, 0.0f, 0.0f, 0.0f};
    const char* ysrc = reinterpret_cast<const char*>(Bp) + (size_t)yc * YCH * 64;

    // T14 split staging: issue next sub-chunk's global load early (regs),
    // ds_write after the barrier; latency hides under current MFMA phase.
    uint4 ld = *reinterpret_cast<const uint4*>(ysrc + tid * 16);
#pragma unroll 1
    for (int sc = 0; sc < NSUB; ++sc) {
        __syncthreads();  // buf[sc&1] was last read 2 phases ago
        *reinterpret_cast<uint4*>(&lbuf[sc & 1][tid * 16]) = ld;
        if (sc + 1 < NSUB)
            ld = *reinterpret_cast<const uint4*>(
                ysrc + (size_t)(sc + 1) * (SUBPTS * 64) + tid * 16);
        __syncthreads();  // buf[sc&1] ready
        const char* buf = lbuf[sc & 1];
#pragma unroll
        for (int t = 0; t < SUBT; t += 2) {
            bf16x8 b0 = *reinterpret_cast<const bf16x8*>(
                buf + ((t + 0) * 16 + col) * 64 + kg * 16);
            bf16x8 b1 = *reinterpret_cast<const bf16x8*>(
                buf + ((t + 1) * 16 + col) * 64 + kg * 16);
#pragma unroll
            for (int xi = 0; xi < XT_W; ++xi) {
                f32x4 A = __builtin_amdgcn_mfma_f32_16x16x32_bf16(af[xi], b0, z4, 0, 0, 0);
                f32x4 B = __builtin_amdgcn_mfma_f32_16x16x32_bf16(af[xi], b1, z4, 0, 0, 0);
                rmax[xi].x = fmaxf(fmaxf(A.x, B.x), rmax[xi].x);  // v_max3_f32
                rmax[xi].y = fmaxf(fmaxf(A.y, B.y), rmax[xi].y);
                rmax[xi].z = fmaxf(fmaxf(A.z, B.z), rmax[xi].z);
                rmax[xi].w = fmaxf(fmaxf(A.w, B.w), rmax[xi].w);
            }
        }
    }

    // col-reduce (over the 16 y-cols of each tile) via DPP; then one plain
    // store per output row into this (dir,yc) partial-min slice.
    float* pslice = part + (size_t)(dir * NYCH + yc) * NPTS;
#pragma unroll
    for (int xi = 0; xi < XT_W; ++xi) {
#define FLUSH(R, COMP)                                                        \
        {                                                                     \
            float v = rmax[xi].COMP;                                          \
            v = rormax<0x121>(v);                                             \
            v = rormax<0x122>(v);                                             \
            v = rormax<0x124>(v);                                             \
            v = rormax<0x128>(v);                                             \
            if (col == 0) {                                                   \
                float d2 = fmaxf(-2.0f * v, 0.0f); /* acc = -d2/2 */          \
                pslice[(xt0 + xi) * 16 + kg * 4 + R] = d2;                    \
            }                                                                 \
        }
        FLUSH(0, x) FLUSH(1, y) FLUSH(2, z) FLUSH(3, w)
#undef FLUSH
    }
}

__global__ __launch_bounds__(256) void chamfer_reduce(
        const float* __restrict__ part, float* __restrict__ out) {
    const int gid = blockIdx.x * 256 + threadIdx.x;  // 128 blocks x 256
    const int dir = gid >> 14, x = gid & (NPTS - 1);
    float m = 3.0e38f;
#pragma unroll
    for (int c = 0; c < NYCH; ++c)
        m = fminf(m, part[(size_t)(dir * NYCH + c) * NPTS + x]);
    float s = sqrtf(m);
#pragma unroll
    for (int off = 32; off > 0; off >>= 1)
        s += __shfl_down(s, off, 64);
    if ((threadIdx.x & 63) == 0)
        atomicAdd(out, s * (1.0f / (float)NPTS));
}

extern "C" void kernel_launch(void* const* d_in, const int* in_sizes, int n_in,
                              void* d_out, int out_size, void* d_ws, size_t ws_size,
                              hipStream_t stream) {
    const float* pred = (const float*)d_in[0];
    const float* gt   = (const float*)d_in[1];
    float* out        = (float*)d_out;
    unsigned short* Ppa = (unsigned short*)d_ws;
    unsigned short* Pgb = (unsigned short*)((char*)d_ws + WS_PGB);
    unsigned short* Pga = (unsigned short*)((char*)d_ws + WS_PGA);
    unsigned short* Ppb = (unsigned short*)((char*)d_ws + WS_PPB);
    float* part         = (float*)((char*)d_ws + WS_PART);

    hipMemsetAsync(d_out, 0, sizeof(float), stream);
    hipLaunchKernelGGL(pack_points, dim3(NPTS / 256), dim3(256), 0, stream,
                       pred, gt, Ppa, Pgb, Pga, Ppb);
    hipLaunchKernelGGL(chamfer_part, dim3(NXB, NYCH, 2), dim3(BLOCKB), 0, stream,
                       Ppa, Pgb, Pga, Ppb, part);
    hipLaunchKernelGGL(chamfer_reduce, dim3(2 * NPTS / 256), dim3(256), 0, stream,
                       part, out);
}